// Round 15
// baseline (70.806 us; speedup 1.0000x reference)
//
#include <hip/hip_runtime.h>
#include <hip/hip_bf16.h>

// AgentModel: B=8, N=256, TD=128, LH=128, H=128, A=5, L=2
constexpr int Nc = 256;
constexpr int Hc = 128;
constexpr int Ac = 5;
constexpr int Mc = 2048;
constexpr int R = 8;       // rows per block
constexpr int GRID = 256;  // 256 blocks, 1 block/CU

// Block -> (batch, slice): b = blk&7 so all 32 blocks of a batch land on one
// XCD (round-robin dispatch) -> batch pj slice stays in that XCD's L2.
__device__ __forceinline__ void rowmap(int blk, int& b, int& sl, int& m0) {
  b = blk & 7;
  sl = blk >> 3;
  m0 = b * 256 + sl * 8;
}

// ---------------------------------------------------------------------------
// K1: encoder + pj/pi of layer 0.  256 threads (proven).
// ---------------------------------------------------------------------------
__global__ __launch_bounds__(256) void k1_enc_pjpi(
    const float* __restrict__ theta, const float* __restrict__ cell,
    const float* __restrict__ encW, const float* __restrict__ encb,
    const float* __restrict__ msgW0, float* __restrict__ h,
    float* __restrict__ pj, float* __restrict__ pi) {
  __shared__ float xs[R][256];
  __shared__ float hs[R][Hc];
  int b, sl, m0;
  rowmap(blockIdx.x, b, sl, m0);
  const int tid = threadIdx.x;

  for (int idx = tid * 4; idx < R * 256; idx += 256 * 4) {
    int r = idx >> 8, d = idx & 255;
    const float* src = (d < 128) ? theta + (m0 + r) * 128 + d
                                 : cell + (m0 + r) * 128 + (d - 128);
    *reinterpret_cast<float4*>(&xs[r][d]) = *reinterpret_cast<const float4*>(src);
  }
  __syncthreads();

  const int o = tid & 127;
  const int rg = tid >> 7;  // 0..1 -> rows rg*4 .. rg*4+3
  {
    float acc[4] = {0, 0, 0, 0};
    const float* wr = encW + o * 256;
#pragma unroll 8
    for (int k = 0; k < 256; k += 4) {
      float4 w = *reinterpret_cast<const float4*>(wr + k);
#pragma unroll
      for (int r = 0; r < 4; ++r) {
        const float* x = &xs[rg * 4 + r][k];
        acc[r] += w.x * x[0] + w.y * x[1] + w.z * x[2] + w.w * x[3];
      }
    }
    const float bb = encb[o];
#pragma unroll
    for (int r = 0; r < 4; ++r) {
      float v = fmaxf(acc[r] + bb, 0.f);
      hs[rg * 4 + r][o] = v;
      h[(m0 + rg * 4 + r) * Hc + o] = v;
    }
  }
  __syncthreads();

  {  // pj/pi layer 0: 256 cols x 8 rows
    const int c = tid;
    const float* wr = msgW0 + (c & 127) * 256 + ((c >> 7) << 7);
    float a[R];
#pragma unroll
    for (int r = 0; r < R; ++r) a[r] = 0.f;
#pragma unroll 8
    for (int k = 0; k < 128; k += 4) {
      float4 w = *reinterpret_cast<const float4*>(wr + k);
#pragma unroll
      for (int r = 0; r < R; ++r) {
        const float* x = &hs[r][k];
        a[r] += w.x * x[0] + w.y * x[1] + w.z * x[2] + w.w * x[3];
      }
    }
    float* dst = (c < 128) ? pj : pi;
    const int oc = c & 127;
#pragma unroll
    for (int r = 0; r < R; ++r) dst[(m0 + r) * Hc + oc] = a[r];
  }
}

// ---------------------------------------------------------------------------
// K2/K3 (512 threads, 2 waves/SIMD): agg(l)+upd(l) [+ pjpi(l+1) | + head]
// agg: stage full 128 KB batch pj slice (16 float4/thread); thread
// (q=col-quad, rr=j-range of 16) reads each stage float4 exactly once,
// accumulating all 8 rows. 16 partial sets reduced by threads rr<8 via LDS
// (disjoint dead-stage region). sum_j relu(v+s)=0.5*(sum v+256s+sum|v+s|).
// ---------------------------------------------------------------------------
template <bool LAST>
__global__ __launch_bounds__(512) void k_layer(
    const float* __restrict__ pj, const float* __restrict__ pi,
    const float* __restrict__ mb, float* __restrict__ h,
    const float* __restrict__ updWl, const float* __restrict__ updbl,
    const float* __restrict__ msgW2, float* __restrict__ pj2,
    float* __restrict__ pi2, const float* __restrict__ hW1,
    const float* __restrict__ hb1, const float* __restrict__ hW2,
    const float* __restrict__ hb2, float* __restrict__ out) {
  __shared__ float smem[Nc * Hc];  // 128 KB: pj slice; later partials/xs/hs/zs
  int b, sl, m0;
  rowmap(blockIdx.x, b, sl, m0);
  const int tid = threadIdx.x;
  const float* pjb = pj + b * Nc * Hc;

  {  // ---- stage whole batch slice: 16 float4/thread, coalesced ----
    const float4* src = reinterpret_cast<const float4*>(pjb);
    float4* dst = reinterpret_cast<float4*>(smem);
#pragma unroll
    for (int i = 0; i < 16; ++i) dst[i * 512 + tid] = src[i * 512 + tid];
  }

  const int q = tid & 31;   // col-quad
  const int rr = tid >> 5;  // j-range 0..15
  const int o4 = q * 4;
  float sA[8][4];
  {
    float4 m4 = *reinterpret_cast<const float4*>(mb + o4);
#pragma unroll
    for (int row = 0; row < 8; ++row) {
      float4 p4 = *reinterpret_cast<const float4*>(pi + (m0 + row) * Hc + o4);
      sA[row][0] = p4.x + m4.x;
      sA[row][1] = p4.y + m4.y;
      sA[row][2] = p4.z + m4.z;
      sA[row][3] = p4.w + m4.w;
    }
  }
  float he[4] = {0.f, 0.f, 0.f, 0.f};
  if (rr < 8) {
    float4 h4 = *reinterpret_cast<const float4*>(h + (m0 + rr) * Hc + o4);
    he[0] = h4.x; he[1] = h4.y; he[2] = h4.z; he[3] = h4.w;
  }
  __syncthreads();  // stage complete

  // ---- j-loop: 16 j's, each stage float4 read once, all 8 rows ----
  float vs[4] = {0.f, 0.f, 0.f, 0.f};
  float ab[8][4] = {};
  const int j0 = rr * 16;
#pragma unroll 4
  for (int jj = 0; jj < 16; ++jj) {
    float4 v4 = *reinterpret_cast<const float4*>(&smem[(j0 + jj) * Hc + o4]);
    float ve[4] = {v4.x, v4.y, v4.z, v4.w};
#pragma unroll
    for (int e = 0; e < 4; ++e) vs[e] += ve[e];
#pragma unroll
    for (int row = 0; row < 8; ++row)
#pragma unroll
      for (int e = 0; e < 4; ++e) ab[row][e] += fabsf(ve[e] + sA[row][e]);
  }
  // diag for own row (rr<8), while stage intact
  float de[4] = {0.f, 0.f, 0.f, 0.f};
  if (rr < 8) {
    float4 d4 = *reinterpret_cast<const float4*>(&smem[(sl * 8 + rr) * Hc + o4]);
    de[0] = d4.x; de[1] = d4.y; de[2] = d4.z; de[3] = d4.w;
  }
  __syncthreads();  // all stage reads done

  // ---- write 16 partial sets into dead stage region ----
  // AB[set][row][q4] at set*1024 + row*128 + q*4 (0..16383)
  // VS[set][q4]      at 16384 + set*128 + q*4   (16384..18431)
#pragma unroll
  for (int row = 0; row < 8; ++row)
    *reinterpret_cast<float4*>(&smem[rr * 1024 + row * 128 + o4]) =
        make_float4(ab[row][0], ab[row][1], ab[row][2], ab[row][3]);
  *reinterpret_cast<float4*>(&smem[16384 + rr * 128 + o4]) =
      make_float4(vs[0], vs[1], vs[2], vs[3]);
  __syncthreads();

  float* xsm = smem + 18432;  // [8][128]
  float* hsm = smem + 19456;  // [8][128]
  float* zsm = smem + 20480;  // [8][128] (LAST only)
  if (rr < 8) {  // ---- reduce 16 sets for (row=rr, col-quad q) ----
    float AB[4] = {0.f, 0.f, 0.f, 0.f}, VS[4] = {0.f, 0.f, 0.f, 0.f};
#pragma unroll
    for (int s16 = 0; s16 < 16; ++s16) {
      float4 a4 =
          *reinterpret_cast<const float4*>(&smem[s16 * 1024 + rr * 128 + o4]);
      float4 v4 =
          *reinterpret_cast<const float4*>(&smem[16384 + s16 * 128 + o4]);
      AB[0] += a4.x; AB[1] += a4.y; AB[2] += a4.z; AB[3] += a4.w;
      VS[0] += v4.x; VS[1] += v4.y; VS[2] += v4.z; VS[3] += v4.w;
    }
    float xv[4];
#pragma unroll
    for (int e = 0; e < 4; ++e) {
      float dg = fmaxf(de[e] + sA[rr][e], 0.f);
      float sr = 0.5f * (VS[e] + 256.f * sA[rr][e] + AB[e]);
      xv[e] = he[e] + (sr - dg) * (1.f / 255.f);
    }
    *reinterpret_cast<float4*>(&xsm[rr * Hc + o4]) =
        make_float4(xv[0], xv[1], xv[2], xv[3]);
  }
  __syncthreads();

  const int o = tid & 127;
  const int rg = tid >> 7;  // 0..3 -> rows rg*2, rg*2+1
  {  // ---- update GEMM: 2 rows/thread ----
    const int r0 = rg * 2;
    float a0 = 0.f, a1 = 0.f;
    const float* wr = updWl + o * Hc;
#pragma unroll 8
    for (int k = 0; k < 128; k += 4) {
      float4 w = *reinterpret_cast<const float4*>(wr + k);
      const float* x0 = &xsm[r0 * Hc + k];
      const float* x1 = &xsm[(r0 + 1) * Hc + k];
      a0 += w.x * x0[0] + w.y * x0[1] + w.z * x0[2] + w.w * x0[3];
      a1 += w.x * x1[0] + w.y * x1[1] + w.z * x1[2] + w.w * x1[3];
    }
    const float bo = updbl[o];
    float v0 = fmaxf(a0 + bo, 0.f), v1 = fmaxf(a1 + bo, 0.f);
    hsm[r0 * Hc + o] = v0;
    hsm[(r0 + 1) * Hc + o] = v1;
    if (!LAST) {
      h[(m0 + r0) * Hc + o] = v0;
      h[(m0 + r0 + 1) * Hc + o] = v1;
    }
  }
  __syncthreads();

  if (!LAST) {  // ---- pj/pi next layer: 256 cols x 2 halves of 4 rows ----
    const int c = tid & 255;
    const int half = tid >> 8;
    const int rb = half * 4;
    const float* wr = msgW2 + (c & 127) * 256 + ((c >> 7) << 7);
    float a[4] = {0.f, 0.f, 0.f, 0.f};
#pragma unroll 8
    for (int k = 0; k < 128; k += 4) {
      float4 w = *reinterpret_cast<const float4*>(wr + k);
#pragma unroll
      for (int r2 = 0; r2 < 4; ++r2) {
        const float* x = &hsm[(rb + r2) * Hc + k];
        a[r2] += w.x * x[0] + w.y * x[1] + w.z * x[2] + w.w * x[3];
      }
    }
    float* dst = (c < 128) ? pj2 : pi2;
    const int oc = c & 127;
#pragma unroll
    for (int r2 = 0; r2 < 4; ++r2) dst[(m0 + rb + r2) * Hc + oc] = a[r2];
  } else {  // ---- head: 2 rows/thread ----
    const int r0 = rg * 2;
    float a0 = 0.f, a1 = 0.f;
    const float* wr = hW1 + o * Hc;
#pragma unroll 8
    for (int k = 0; k < 128; k += 4) {
      float4 w = *reinterpret_cast<const float4*>(wr + k);
      const float* x0 = &hsm[r0 * Hc + k];
      const float* x1 = &hsm[(r0 + 1) * Hc + k];
      a0 += w.x * x0[0] + w.y * x0[1] + w.z * x0[2] + w.w * x0[3];
      a1 += w.x * x1[0] + w.y * x1[1] + w.z * x1[2] + w.w * x1[3];
    }
    const float bo = hb1[o];
    zsm[r0 * Hc + o] = fmaxf(a0 + bo, 0.f);
    zsm[(r0 + 1) * Hc + o] = fmaxf(a1 + bo, 0.f);
    __syncthreads();

    if (tid < R * Ac) {  // 40 dots of length 128
      const int r2 = tid / Ac;
      const int a2 = tid % Ac;
      const float* wr2 = hW2 + a2 * Hc;
      float sacc = 0.f;
#pragma unroll 8
      for (int k = 0; k < 128; k += 4) {
        float4 w = *reinterpret_cast<const float4*>(wr2 + k);
        const float* z = &zsm[r2 * Hc + k];
        sacc += w.x * z[0] + w.y * z[1] + w.z * z[2] + w.w * z[3];
      }
      out[(m0 + r2) * Ac + a2] = sacc + hb2[a2];
    }
  }
}

// ---------------------------------------------------------------------------
extern "C" void kernel_launch(void* const* d_in, const int* in_sizes, int n_in,
                              void* d_out, int out_size, void* d_ws, size_t ws_size,
                              hipStream_t stream) {
  const float* theta = (const float*)d_in[0];
  const float* cell  = (const float*)d_in[1];
  const float* encW  = (const float*)d_in[2];
  const float* encb  = (const float*)d_in[3];
  const float* msgW  = (const float*)d_in[4];   // (2,128,256)
  const float* msgb  = (const float*)d_in[5];   // (2,128)
  const float* updW  = (const float*)d_in[6];   // (2,128,128)
  const float* updb  = (const float*)d_in[7];   // (2,128)
  const float* hW1   = (const float*)d_in[8];
  const float* hb1   = (const float*)d_in[9];
  const float* hW2   = (const float*)d_in[10];
  const float* hb2   = (const float*)d_in[11];
  float* out = (float*)d_out;

  float* ws = (float*)d_ws;
  const int MH = Mc * Hc;  // 262144
  float* h   = ws;
  float* pjA = ws + MH;
  float* piA = ws + 2 * MH;
  float* pjB = ws + 3 * MH;
  float* piB = ws + 4 * MH;

  k1_enc_pjpi<<<GRID, 256, 0, stream>>>(theta, cell, encW, encb, msgW, h, pjA,
                                        piA);
  k_layer<false><<<GRID, 512, 0, stream>>>(pjA, piA, msgb, h, updW, updb,
                                           msgW + 32768, pjB, piB, hW1, hb1,
                                           hW2, hb2, out);
  k_layer<true><<<GRID, 512, 0, stream>>>(pjB, piB, msgb + Hc, h, updW + 16384,
                                          updb + Hc, nullptr, nullptr, nullptr,
                                          hW1, hb1, hW2, hb2, out);
}

// Round 16
// 59.591 us; speedup vs baseline: 1.1882x; 1.1882x over previous
//
#include <hip/hip_runtime.h>
#include <hip/hip_bf16.h>

// AgentModel: B=8, N=256, TD=128, LH=128, H=128, A=5, L=2
constexpr int Nc = 256;
constexpr int Hc = 128;
constexpr int Ac = 5;
constexpr int Mc = 2048;
constexpr int R = 8;       // rows per block
constexpr int GRID = 256;  // 256 blocks x 256 threads, 1 block/CU

// Block -> (batch, slice): b = blk&7 so all 32 blocks of a batch land on one
// XCD (round-robin dispatch) -> batch pj slice stays in that XCD's L2.
__device__ __forceinline__ void rowmap(int blk, int& b, int& sl, int& m0) {
  b = blk & 7;
  sl = blk >> 3;
  m0 = b * 256 + sl * 8;
}

// ---------------------------------------------------------------------------
// K1: encoder + pj/pi of layer 0.  (proven)
// ---------------------------------------------------------------------------
__global__ __launch_bounds__(256) void k1_enc_pjpi(
    const float* __restrict__ theta, const float* __restrict__ cell,
    const float* __restrict__ encW, const float* __restrict__ encb,
    const float* __restrict__ msgW0, float* __restrict__ h,
    float* __restrict__ pj, float* __restrict__ pi) {
  __shared__ float xs[R][256];
  __shared__ float hs[R][Hc];
  int b, sl, m0;
  rowmap(blockIdx.x, b, sl, m0);
  const int tid = threadIdx.x;

  for (int idx = tid * 4; idx < R * 256; idx += 256 * 4) {
    int r = idx >> 8, d = idx & 255;
    const float* src = (d < 128) ? theta + (m0 + r) * 128 + d
                                 : cell + (m0 + r) * 128 + (d - 128);
    *reinterpret_cast<float4*>(&xs[r][d]) = *reinterpret_cast<const float4*>(src);
  }
  __syncthreads();

  const int o = tid & 127;
  const int rg = tid >> 7;  // 0..1 -> rows rg*4 .. rg*4+3
  {
    float acc[4] = {0, 0, 0, 0};
    const float* wr = encW + o * 256;
#pragma unroll 8
    for (int k = 0; k < 256; k += 4) {
      float4 w = *reinterpret_cast<const float4*>(wr + k);
#pragma unroll
      for (int r = 0; r < 4; ++r) {
        const float* x = &xs[rg * 4 + r][k];
        acc[r] += w.x * x[0] + w.y * x[1] + w.z * x[2] + w.w * x[3];
      }
    }
    const float bb = encb[o];
#pragma unroll
    for (int r = 0; r < 4; ++r) {
      float v = fmaxf(acc[r] + bb, 0.f);
      hs[rg * 4 + r][o] = v;
      h[(m0 + rg * 4 + r) * Hc + o] = v;
    }
  }
  __syncthreads();

  {  // pj/pi layer 0: 256 cols x 8 rows
    const int c = tid;
    const float* wr = msgW0 + (c & 127) * 256 + ((c >> 7) << 7);
    float a[R];
#pragma unroll
    for (int r = 0; r < R; ++r) a[r] = 0.f;
#pragma unroll 8
    for (int k = 0; k < 128; k += 4) {
      float4 w = *reinterpret_cast<const float4*>(wr + k);
#pragma unroll
      for (int r = 0; r < R; ++r) {
        const float* x = &hs[r][k];
        a[r] += w.x * x[0] + w.y * x[1] + w.z * x[2] + w.w * x[3];
      }
    }
    float* dst = (c < 128) ? pj : pi;
    const int oc = c & 127;
#pragma unroll
    for (int r = 0; r < R; ++r) dst[(m0 + r) * Hc + oc] = a[r];
  }
}

// ---------------------------------------------------------------------------
// K2/K3: agg(l)+upd(l) [+ pjpi(l+1) | + head]
// agg: stage the full 128 KB batch pj slice; thread (q=col-quad, r=j-range)
// processes 32 j's for ALL 8 rows (each stage float4 read exactly once).
// Partials (ab[8][4], vs[4]) reduced across the 8 j-range threads via LDS.
// sum_j relu(v+s) = 0.5*(sum v + 256*s + sum|v+s|); diag from LDS.
// ---------------------------------------------------------------------------
template <bool LAST>
__global__ __launch_bounds__(256) void k_layer(
    const float* __restrict__ pj, const float* __restrict__ pi,
    const float* __restrict__ mb, float* __restrict__ h,
    const float* __restrict__ updWl, const float* __restrict__ updbl,
    const float* __restrict__ msgW2, float* __restrict__ pj2,
    float* __restrict__ pi2, const float* __restrict__ hW1,
    const float* __restrict__ hb1, const float* __restrict__ hW2,
    const float* __restrict__ hb2, float* __restrict__ out) {
  __shared__ float smem[Nc * Hc];  // 128 KB: pj slice; later partials/xs/hs/zs
  int b, sl, m0;
  rowmap(blockIdx.x, b, sl, m0);
  const int tid = threadIdx.x;
  const float* pjb = pj + b * Nc * Hc;

  {  // ---- stage whole batch slice: 32 float4/thread, coalesced ----
    const float4* src = reinterpret_cast<const float4*>(pjb);
    float4* dst = reinterpret_cast<float4*>(smem);
#pragma unroll
    for (int i = 0; i < 32; ++i) dst[i * 256 + tid] = src[i * 256 + tid];
  }

  // ---- per-thread setup: q = col-quad, r = j-range (and own row id) ----
  const int q = tid & 31;
  const int r = tid >> 5;  // 0..7
  const int o4 = q * 4;
  float sA[8][4];  // s for all 8 rows of this col-quad
  {
    float4 m4 = *reinterpret_cast<const float4*>(mb + o4);
#pragma unroll
    for (int row = 0; row < 8; ++row) {
      float4 p4 = *reinterpret_cast<const float4*>(pi + (m0 + row) * Hc + o4);
      sA[row][0] = p4.x + m4.x;
      sA[row][1] = p4.y + m4.y;
      sA[row][2] = p4.z + m4.z;
      sA[row][3] = p4.w + m4.w;
    }
  }
  float4 h4 = *reinterpret_cast<const float4*>(h + (m0 + r) * Hc + o4);

  __syncthreads();  // stage complete

  // ---- j-loop: 32 j's, each float4 read once, all 8 rows accumulated ----
  float vs[4] = {0.f, 0.f, 0.f, 0.f};
  float ab[8][4] = {};
  const int j0 = r * 32;
#pragma unroll 4
  for (int jj = 0; jj < 32; ++jj) {
    float4 v4 = *reinterpret_cast<const float4*>(&smem[(j0 + jj) * Hc + o4]);
    float ve[4] = {v4.x, v4.y, v4.z, v4.w};
#pragma unroll
    for (int e = 0; e < 4; ++e) vs[e] += ve[e];
#pragma unroll
    for (int row = 0; row < 8; ++row)
#pragma unroll
      for (int e = 0; e < 4; ++e) ab[row][e] += fabsf(ve[e] + sA[row][e]);
  }
  // diag for own row r (batch-row sl*8+r), while stage is intact
  float4 d4 = *reinterpret_cast<const float4*>(&smem[(sl * 8 + r) * Hc + o4]);
  float de[4] = {d4.x, d4.y, d4.z, d4.w};
  float he[4] = {h4.x, h4.y, h4.z, h4.w};
  __syncthreads();  // all stage reads done

  // ---- write partials into dead stage region ----
  // AB at float idx row*1024 + r*128 + q*4 ; VS at 8192 + r*128 + q*4
#pragma unroll
  for (int row = 0; row < 8; ++row)
    *reinterpret_cast<float4*>(&smem[row * 1024 + r * 128 + q * 4]) =
        make_float4(ab[row][0], ab[row][1], ab[row][2], ab[row][3]);
  *reinterpret_cast<float4*>(&smem[8192 + r * 128 + q * 4]) =
      make_float4(vs[0], vs[1], vs[2], vs[3]);
  __syncthreads();

  // ---- reduce: thread (q, row=r) sums partials for its (row, col-quad) ----
  float AB[4] = {0.f, 0.f, 0.f, 0.f}, VS[4] = {0.f, 0.f, 0.f, 0.f};
#pragma unroll
  for (int rr = 0; rr < 8; ++rr) {
    float4 a4 = *reinterpret_cast<const float4*>(
        &smem[r * 1024 + rr * 128 + q * 4]);
    float4 v4 = *reinterpret_cast<const float4*>(&smem[8192 + rr * 128 + q * 4]);
    AB[0] += a4.x; AB[1] += a4.y; AB[2] += a4.z; AB[3] += a4.w;
    VS[0] += v4.x; VS[1] += v4.y; VS[2] += v4.z; VS[3] += v4.w;
  }
  float xv[4];
#pragma unroll
  for (int e = 0; e < 4; ++e) {
    float dg = fmaxf(de[e] + sA[r][e], 0.f);
    float sr = 0.5f * (VS[e] + 256.f * sA[r][e] + AB[e]);
    xv[e] = he[e] + (sr - dg) * (1.f / 255.f);
  }
  __syncthreads();  // partial reads done; smem reusable

  float* xsm = smem;         // [8][128]
  float* hsm = smem + 1024;  // [8][128]
  float* zsm = smem + 2048;  // [8][128] (LAST only)
  *reinterpret_cast<float4*>(&xsm[r * Hc + o4]) =
      make_float4(xv[0], xv[1], xv[2], xv[3]);
  __syncthreads();

  const int o = tid & 127;
  const int rg = tid >> 7;  // 0..1 -> rows rg*4 .. rg*4+3
  {  // ---- update GEMM ----
    float a[4] = {0, 0, 0, 0};
    const float* wr = updWl + o * Hc;
#pragma unroll 8
    for (int k = 0; k < 128; k += 4) {
      float4 w = *reinterpret_cast<const float4*>(wr + k);
#pragma unroll
      for (int rr = 0; rr < 4; ++rr) {
        const float* x = &xsm[(rg * 4 + rr) * Hc + k];
        a[rr] += w.x * x[0] + w.y * x[1] + w.z * x[2] + w.w * x[3];
      }
    }
    const float bo = updbl[o];
#pragma unroll
    for (int rr = 0; rr < 4; ++rr) {
      float v = fmaxf(a[rr] + bo, 0.f);
      hsm[(rg * 4 + rr) * Hc + o] = v;
      if (!LAST) h[(m0 + rg * 4 + rr) * Hc + o] = v;
    }
  }
  __syncthreads();

  if (!LAST) {  // ---- pj/pi next layer: 256 cols x 8 rows ----
    const int c = tid;
    const float* wr = msgW2 + (c & 127) * 256 + ((c >> 7) << 7);
    float a[R];
#pragma unroll
    for (int rr = 0; rr < R; ++rr) a[rr] = 0.f;
#pragma unroll 8
    for (int k = 0; k < 128; k += 4) {
      float4 w = *reinterpret_cast<const float4*>(wr + k);
#pragma unroll
      for (int rr = 0; rr < R; ++rr) {
        const float* x = &hsm[rr * Hc + k];
        a[rr] += w.x * x[0] + w.y * x[1] + w.z * x[2] + w.w * x[3];
      }
    }
    float* dst = (c < 128) ? pj2 : pi2;
    const int oc = c & 127;
#pragma unroll
    for (int rr = 0; rr < R; ++rr) dst[(m0 + rr) * Hc + oc] = a[rr];
  } else {  // ---- head ----
    float a[4] = {0, 0, 0, 0};
    const float* wr = hW1 + o * Hc;
#pragma unroll 8
    for (int k = 0; k < 128; k += 4) {
      float4 w = *reinterpret_cast<const float4*>(wr + k);
#pragma unroll
      for (int rr = 0; rr < 4; ++rr) {
        const float* x = &hsm[(rg * 4 + rr) * Hc + k];
        a[rr] += w.x * x[0] + w.y * x[1] + w.z * x[2] + w.w * x[3];
      }
    }
    const float bo = hb1[o];
#pragma unroll
    for (int rr = 0; rr < 4; ++rr)
      zsm[(rg * 4 + rr) * Hc + o] = fmaxf(a[rr] + bo, 0.f);
    __syncthreads();

    if (tid < R * Ac) {  // 40 dots of length 128
      const int rr = tid / Ac;
      const int a2 = tid % Ac;
      const float* wr2 = hW2 + a2 * Hc;
      float sacc = 0.f;
#pragma unroll 8
      for (int k = 0; k < 128; k += 4) {
        float4 w = *reinterpret_cast<const float4*>(wr2 + k);
        const float* z = &zsm[rr * Hc + k];
        sacc += w.x * z[0] + w.y * z[1] + w.z * z[2] + w.w * z[3];
      }
      out[(m0 + rr) * Ac + a2] = sacc + hb2[a2];
    }
  }
}

// ---------------------------------------------------------------------------
extern "C" void kernel_launch(void* const* d_in, const int* in_sizes, int n_in,
                              void* d_out, int out_size, void* d_ws, size_t ws_size,
                              hipStream_t stream) {
  const float* theta = (const float*)d_in[0];
  const float* cell  = (const float*)d_in[1];
  const float* encW  = (const float*)d_in[2];
  const float* encb  = (const float*)d_in[3];
  const float* msgW  = (const float*)d_in[4];   // (2,128,256)
  const float* msgb  = (const float*)d_in[5];   // (2,128)
  const float* updW  = (const float*)d_in[6];   // (2,128,128)
  const float* updb  = (const float*)d_in[7];   // (2,128)
  const float* hW1   = (const float*)d_in[8];
  const float* hb1   = (const float*)d_in[9];
  const float* hW2   = (const float*)d_in[10];
  const float* hb2   = (const float*)d_in[11];
  float* out = (float*)d_out;

  float* ws = (float*)d_ws;
  const int MH = Mc * Hc;  // 262144
  float* h   = ws;
  float* pjA = ws + MH;
  float* piA = ws + 2 * MH;
  float* pjB = ws + 3 * MH;
  float* piB = ws + 4 * MH;

  k1_enc_pjpi<<<GRID, 256, 0, stream>>>(theta, cell, encW, encb, msgW, h, pjA,
                                        piA);
  k_layer<false><<<GRID, 256, 0, stream>>>(pjA, piA, msgb, h, updW, updb,
                                           msgW + 32768, pjB, piB, hW1, hb1,
                                           hW2, hb2, out);
  k_layer<true><<<GRID, 256, 0, stream>>>(pjB, piB, msgb + Hc, h, updW + 16384,
                                          updb + Hc, nullptr, nullptr, nullptr,
                                          hW1, hb1, hW2, hb2, out);
}